// Round 12
// baseline (160.181 us; speedup 1.0000x reference)
//
#include <hip/hip_runtime.h>
#include <math.h>

#define BB 16
#define TT 4096
#define EE 1024
#define HALF 2048
#define WIN 15
#define EPSF 1e-6f
#define PI_F   3.14159265358979323846f
#define PIO2_F 1.57079632679489662f

// Branchless cephes-style asin: ~16 VALU ops, 1 sqrt, no divergence.
__device__ __forceinline__ float fast_asinf(float v) {
    float a  = fabsf(v);
    float z1 = a * a;
    float z2 = 0.5f * (1.0f - a);
    bool big = a > 0.5f;
    float z = big ? z2 : z1;
    float s = big ? sqrtf(z) : a;
    float p = fmaf(z, 4.2163199048e-2f, 2.4181311049e-2f);
    p = fmaf(z, p, 4.5470025998e-2f);
    p = fmaf(z, p, 7.4953002686e-2f);
    p = fmaf(z, p, 1.6666752422e-1f);
    float r = fmaf(s * z, p, s);
    float rb = fmaf(-2.0f, r, PIO2_F);
    r = big ? rb : r;
    return copysignf(r, v);
}

// ---------------------------------------------------------------------------
// Phase + fused tdiff (R9 structure, unchanged) + barrier-counter reset.
// ---------------------------------------------------------------------------
__global__ void phase_tdiff_kernel(const float* __restrict__ x,
                                   const float* __restrict__ taper,
                                   float* __restrict__ phases_b,
                                   float* __restrict__ tdiff_b,
                                   int* __restrict__ barrier_ctr) {
    if (blockIdx.x == 0 && threadIdx.x == 0) *barrier_ctr = 0;  // re-arm each call

    const int wave = threadIdx.x >> 6;
    const int lane = threadIdx.x & 63;
    const int row  = blockIdx.x * 4 + wave;      // [0, B*T)
    const int b = row >> 12;
    const int t = row & (TT - 1);
    const float tap = taper[t];
    const float* xr = x + (size_t)row * EE;

    float xd = 0.0f, tapd = 0.0f;
    const int td = t - lane;
    const bool do_d = (lane >= 1) && (lane <= WIN) && (lane <= t);
    if (do_d) {
        xd   = x[((size_t)b * TT + td) * EE];    // element 0 of row t-lane
        tapd = taper[td];
    }

    const float c0 = xr[0] * tap;
    const float r = fabsf(c0) + EPSF;
    const float scale = tap / r;
    const float start = (c0 >= 0.0f) ? 0.0f : PI_F;
    const float LO = -1.0f + EPSF, HI = 1.0f - EPSF;

    const float4* xr4 = (const float4*)xr;
    float sum = 0.0f;
    #pragma unroll
    for (int j = 0; j < 4; ++j) {
        float4 v = xr4[j * 64 + lane];
        float a0 = fast_asinf(fminf(fmaxf(v.x * scale, LO), HI));
        if ((j | lane) == 0) a0 = 0.0f;          // element 0 excluded
        sum += a0;
        sum += fast_asinf(fminf(fmaxf(v.y * scale, LO), HI));
        sum += fast_asinf(fminf(fmaxf(v.z * scale, LO), HI));
        sum += fast_asinf(fminf(fmaxf(v.w * scale, LO), HI));
    }
    #pragma unroll
    for (int off = 32; off > 0; off >>= 1)
        sum += __shfl_xor(sum, off, 64);

    float contrib = do_d ? ((float)lane * xd * tapd) : 0.0f;
    #pragma unroll
    for (int off = 8; off > 0; off >>= 1)
        contrib += __shfl_xor(contrib, off, 64);

    if (lane == 0) {
        phases_b[b * TT + t] = start + sum;
        const int s = (t < WIN) ? t : WIN;
        const float norm = 0.5f * (float)s * (float)(s + 1);
        tdiff_b[b * TT + t] = (norm > 0.0f) ? (contrib / norm) : 0.0f;
    }
}

// ---------------------------------------------------------------------------
// GEMM stage (R9 structure, verbatim): KT=512, double-buffered LDS, counted
// vmcnt pipeline. 512 blocks x 256 threads, 8 cols/block (2/wave).
// MODE 0: silu -> H_b[b*HALF + o].  MODE 1: tanh -> out[b*4096 + o*2 + g].
// ---------------------------------------------------------------------------
__device__ __forceinline__ void gld_lds16(const float* g, float* l) {
    __builtin_amdgcn_global_load_lds(
        (const __attribute__((address_space(1))) unsigned int*)g,
        (__attribute__((address_space(3))) unsigned int*)l,
        16, 0, 0);
}

#define KT_G 512
#define LROW (KT_G + 4)

template <int K, int MODE>
__device__ __forceinline__ void gemm_stage(const float* __restrict__ A0,
                                           const float* __restrict__ W0,
                                           const float* __restrict__ bias0,
                                           float* __restrict__ out0,
                                           const float* __restrict__ A1,
                                           const float* __restrict__ W1,
                                           const float* __restrict__ bias1,
                                           float* __restrict__ out1,
                                           float (*als)[16 * LROW]) {
    constexpr int NT = K / KT_G;

    const int nb = HALF / 8;                      // 256 blocks per problem
    const int g = blockIdx.x / nb;
    const int obase = (blockIdx.x % nb) * 8;

    const float* A    = g ? A1 : A0;
    const float* W    = g ? W1 : W0;
    const float* bias = g ? bias1 : bias0;
    float* out        = g ? out1 : out0;

    const int wv   = threadIdx.x >> 6;            // 0..3
    const int lane = threadIdx.x & 63;
    const int col0 = obase + wv * 2;
    const int col1 = col0 + 1;
    const float* w0p = W + (size_t)col0 * K;
    const float* w1p = W + (size_t)col1 * K;

    auto stage = [&](int t, int s) {
        #pragma unroll
        for (int i = 0; i < 4; ++i) {
            const int br = wv * 4 + i;
            const float* src = A + (size_t)br * K + t * KT_G + lane * 4;
            float* dst = &als[s][br * LROW];      // uniform base; HW adds lane*16B
            gld_lds16(src, dst);
            gld_lds16(src + 256, dst + 256);
        }
    };

    float acc0[16], acc1[16];
    #pragma unroll
    for (int i = 0; i < 16; ++i) { acc0[i] = 0.0f; acc1[i] = 0.0f; }

    stage(0, 0);                                  // 8 ops outstanding

    for (int t = 0; t < NT; ++t) {
        const int cur = t & 1;

        float4 w0v[2], w1v[2];
        #pragma unroll
        for (int s2 = 0; s2 < 2; ++s2) {
            w0v[s2] = *(const float4*)(w0p + t * KT_G + s2 * 256 + lane * 4);
            w1v[s2] = *(const float4*)(w1p + t * KT_G + s2 * 256 + lane * 4);
        }

        if (t + 1 < NT) {
            stage(t + 1, cur ^ 1);                // prefetch next tile
            asm volatile("s_waitcnt vmcnt(8)" ::: "memory");
        } else {
            asm volatile("s_waitcnt vmcnt(0)" ::: "memory");
        }
        __builtin_amdgcn_s_barrier();
        __builtin_amdgcn_sched_barrier(0);

        #pragma unroll
        for (int s2 = 0; s2 < 2; ++s2) {
            #pragma unroll
            for (int br = 0; br < 16; ++br) {
                const float4 a4 = *(const float4*)&als[cur][br * LROW + s2 * 256 + lane * 4];
                acc0[br] += w0v[s2].x*a4.x + w0v[s2].y*a4.y + w0v[s2].z*a4.z + w0v[s2].w*a4.w;
                acc1[br] += w1v[s2].x*a4.x + w1v[s2].y*a4.y + w1v[s2].z*a4.z + w1v[s2].w*a4.w;
            }
        }
        __builtin_amdgcn_sched_barrier(0);
        __builtin_amdgcn_s_barrier();
    }

    #pragma unroll
    for (int off = 32; off > 0; off >>= 1) {
        #pragma unroll
        for (int i = 0; i < 16; ++i) {
            acc0[i] += __shfl_xor(acc0[i], off, 64);
            acc1[i] += __shfl_xor(acc1[i], off, 64);
        }
    }

    const bool isw0 = (lane == 0), isw1 = (lane == 32);
    if (isw0 || isw1) {
        const int o = isw0 ? col0 : col1;
        const float bs = bias[o];
        #pragma unroll
        for (int i = 0; i < 16; ++i) {
            float s = (isw0 ? acc0[i] : acc1[i]) + bs;
            if (MODE == 0) {
                s = s / (1.0f + expf(-s));        // silu
                out[(size_t)i * HALF + o] = s;    // H b-major [16][HALF]
            } else {
                s = tanhf(s);
                out[(size_t)i * (HALF * 2) + o * 2 + g] = s;
            }
        }
    }
}

// ---------------------------------------------------------------------------
// Fused GEMM1+GEMM2 with hand-rolled device-scope grid barrier.
// 512 blocks x 256 threads, 66 KiB LDS -> exactly 2 blocks/CU co-resident
// (512 = capacity), so the spin barrier cannot deadlock. Counter is re-zeroed
// by phase_tdiff_kernel (earlier in the same stream) every call.
// ---------------------------------------------------------------------------
__global__ void __launch_bounds__(256)
gemm_fused_kernel(const float* phases_b, const float* tdiff_b,
                  const float* cW1, const float* cb1,
                  const float* cW2, const float* cb2,
                  const float* pW1, const float* pb1,
                  const float* pW2, const float* pb2,
                  float* H1_b, float* H2_b, float* out,
                  int* barrier_ctr) {
    __shared__ float als[2][16 * LROW];           // 66 KiB

    gemm_stage<TT, 0>(phases_b, cW1, cb1, H1_b, tdiff_b, pW1, pb1, H2_b, als);

    // ---- grid barrier: all H1/H2 stores visible before any block reads them
    __threadfence();                              // release this thread's stores
    __syncthreads();                              // whole block fenced
    if (threadIdx.x == 0) {
        __hip_atomic_fetch_add(barrier_ctr, 1, __ATOMIC_ACQ_REL,
                               __HIP_MEMORY_SCOPE_AGENT);
        while (__hip_atomic_load(barrier_ctr, __ATOMIC_ACQUIRE,
                                 __HIP_MEMORY_SCOPE_AGENT) < 512) {
            __builtin_amdgcn_s_sleep(2);
        }
    }
    __syncthreads();                              // block released together

    gemm_stage<HALF, 1>(H1_b, cW2, cb2, out, H2_b, pW2, pb2, out, als);
}

extern "C" void kernel_launch(void* const* d_in, const int* in_sizes, int n_in,
                              void* d_out, int out_size, void* d_ws, size_t ws_size,
                              hipStream_t stream) {
    const float* x     = (const float*)d_in[0];
    const float* taper = (const float*)d_in[1];
    const float* cW1   = (const float*)d_in[2];
    const float* cb1   = (const float*)d_in[3];
    const float* cW2   = (const float*)d_in[4];
    const float* cb2   = (const float*)d_in[5];
    const float* pW1   = (const float*)d_in[6];
    const float* pb1   = (const float*)d_in[7];
    const float* pW2   = (const float*)d_in[8];
    const float* pb2   = (const float*)d_in[9];
    float* out = (float*)d_out;
    float* ws  = (float*)d_ws;

    float* phases_b = ws;                         // [16][4096]
    float* tdiff_b  = ws + 65536;                 // [16][4096]
    float* H1_b     = ws + 131072;                // [16][2048]
    float* H2_b     = ws + 163840;                // [16][2048]
    int*   barrier_ctr = (int*)(ws + 196608);

    phase_tdiff_kernel<<<BB * TT / 4, 256, 0, stream>>>(x, taper, phases_b,
                                                        tdiff_b, barrier_ctr);
    gemm_fused_kernel<<<512, 256, 0, stream>>>(phases_b, tdiff_b,
                                               cW1, cb1, cW2, cb2,
                                               pW1, pb1, pW2, pb2,
                                               H1_b, H2_b, out, barrier_ctr);
}

// Round 13
// 119.977 us; speedup vs baseline: 1.3351x; 1.3351x over previous
//
#include <hip/hip_runtime.h>
#include <math.h>

#define BB 16
#define TT 4096
#define EE 1024
#define HALF 2048
#define WIN 15
#define EPSF 1e-6f
#define PI_F   3.14159265358979323846f
#define PIO2_F 1.57079632679489662f

// Branchless cephes-style asin: ~16 VALU ops, 1 sqrt, no divergence.
__device__ __forceinline__ float fast_asinf(float v) {
    float a  = fabsf(v);
    float z1 = a * a;
    float z2 = 0.5f * (1.0f - a);
    bool big = a > 0.5f;
    float z = big ? z2 : z1;
    float s = big ? sqrtf(z) : a;
    float p = fmaf(z, 4.2163199048e-2f, 2.4181311049e-2f);
    p = fmaf(z, p, 4.5470025998e-2f);
    p = fmaf(z, p, 7.4953002686e-2f);
    p = fmaf(z, p, 1.6666752422e-1f);
    float r = fmaf(s * z, p, s);
    float rb = fmaf(-2.0f, r, PIO2_F);
    r = big ? rb : r;
    return copysignf(r, v);
}

// ---------------------------------------------------------------------------
// Phase + fused tdiff (R9 structure, proven): wave per row, b-major outputs.
// ---------------------------------------------------------------------------
__global__ void phase_tdiff_kernel(const float* __restrict__ x,
                                   const float* __restrict__ taper,
                                   float* __restrict__ phases_b,
                                   float* __restrict__ tdiff_b) {
    const int wave = threadIdx.x >> 6;
    const int lane = threadIdx.x & 63;
    const int row  = blockIdx.x * 4 + wave;      // [0, B*T)
    const int b = row >> 12;
    const int t = row & (TT - 1);
    const float tap = taper[t];
    const float* xr = x + (size_t)row * EE;

    float xd = 0.0f, tapd = 0.0f;
    const int td = t - lane;
    const bool do_d = (lane >= 1) && (lane <= WIN) && (lane <= t);
    if (do_d) {
        xd   = x[((size_t)b * TT + td) * EE];    // element 0 of row t-lane
        tapd = taper[td];
    }

    const float c0 = xr[0] * tap;
    const float r = fabsf(c0) + EPSF;
    const float scale = tap / r;
    const float start = (c0 >= 0.0f) ? 0.0f : PI_F;
    const float LO = -1.0f + EPSF, HI = 1.0f - EPSF;

    const float4* xr4 = (const float4*)xr;
    float sum = 0.0f;
    #pragma unroll
    for (int j = 0; j < 4; ++j) {
        float4 v = xr4[j * 64 + lane];
        float a0 = fast_asinf(fminf(fmaxf(v.x * scale, LO), HI));
        if ((j | lane) == 0) a0 = 0.0f;          // element 0 excluded
        sum += a0;
        sum += fast_asinf(fminf(fmaxf(v.y * scale, LO), HI));
        sum += fast_asinf(fminf(fmaxf(v.z * scale, LO), HI));
        sum += fast_asinf(fminf(fmaxf(v.w * scale, LO), HI));
    }
    #pragma unroll
    for (int off = 32; off > 0; off >>= 1)
        sum += __shfl_xor(sum, off, 64);

    float contrib = do_d ? ((float)lane * xd * tapd) : 0.0f;
    #pragma unroll
    for (int off = 8; off > 0; off >>= 1)
        contrib += __shfl_xor(contrib, off, 64);

    if (lane == 0) {
        phases_b[b * TT + t] = start + sum;
        const int s = (t < WIN) ? t : WIN;
        const float norm = 0.5f * (float)s * (float)(s + 1);
        tdiff_b[b * TT + t] = (norm > 0.0f) ? (contrib / norm) : 0.0f;
    }
}

// ---------------------------------------------------------------------------
// GEMM (M=16), SPLIT-K: A b-major [16][K]. 512 blocks x 256 threads (4 waves),
// 8 output cols per block. Each wave owns a K-QUARTER of the tile and
// computes ALL 8 cols over it -> LDS reads = staged bytes (no 4x wave
// amplification). KT=512, 2 LDS buffers, weights prefetched 1 tile ahead
// into double-buffered registers (statically indexed), counted vmcnt(16).
// Reduction: 4 DPP row_ror add rounds (16-lane row sums, register-only),
// 4 writer lanes/wave -> 8KB LDS partials, 128-thread final sum.
// MODE 0: silu -> H_b[b*HALF + o].  MODE 1: tanh -> out[b*4096 + o*2 + g].
// ---------------------------------------------------------------------------
__device__ __forceinline__ void gld_lds16(const float* g, float* l) {
    __builtin_amdgcn_global_load_lds(
        (const __attribute__((address_space(1))) unsigned int*)g,
        (__attribute__((address_space(3))) unsigned int*)l,
        16, 0, 0);
}

template <int CTRL>
__device__ __forceinline__ float dpp_ror_add(float v) {
    int r = __builtin_amdgcn_update_dpp(0, __float_as_int(v), CTRL, 0xF, 0xF, false);
    return v + __int_as_float(r);
}

template <int K, int MODE>
__global__ void __launch_bounds__(256)
gemm_kernel(const float* __restrict__ A0, const float* __restrict__ W0,
            const float* __restrict__ bias0, float* __restrict__ out0,
            const float* __restrict__ A1, const float* __restrict__ W1,
            const float* __restrict__ bias1, float* __restrict__ out1) {
    constexpr int KT = 512;
    constexpr int NT = K / KT;                    // 8 (G1) / 4 (G2), even
    constexpr int LR = KT + 4;                    // row stride, 16B-aligned
    __shared__ float als[2][16 * LR];             // 66 KiB -> 2 blocks/CU
    float* redls = &als[0][0];                    // reused for reduction

    const int nb = HALF / 8;                      // 256 blocks per problem
    const int g = blockIdx.x / nb;
    const int obase = (blockIdx.x % nb) * 8;

    const float* A    = g ? A1 : A0;
    const float* W    = g ? W1 : W0;
    const float* bias = g ? bias1 : bias0;
    float* out        = g ? out1 : out0;

    const int wv   = threadIdx.x >> 6;            // 0..3  (K-quarter owner)
    const int lane = threadIdx.x & 63;
    const int kofs = wv * 128 + lane * 2;         // this lane's 2 k's in tile

    const float* wb = W + (size_t)obase * K + kofs;   // + c*K + t*KT

    // stage tile t into buffer t&1: wave wv stages rows wv*4..wv*4+3
    auto stageA = [&](int t) {
        const int s = t & 1;
        #pragma unroll
        for (int i = 0; i < 4; ++i) {
            const int br = wv * 4 + i;
            const float* src = A + (size_t)br * K + t * KT + lane * 4;
            float* dst = &als[s][br * LR];        // uniform base; HW adds lane*16B
            gld_lds16(src, dst);
            gld_lds16(src + 256, dst + 256);
        }
    };

#define LOADW(WREG, T) do {                                               \
        _Pragma("unroll")                                                 \
        for (int c = 0; c < 8; ++c)                                       \
            WREG[c] = *(const float2*)(wb + (size_t)c * K + (T) * KT);    \
    } while (0)

#define COMPUTE(S, WREG) do {                                             \
        _Pragma("unroll")                                                 \
        for (int b = 0; b < 16; ++b) {                                    \
            const float2 a2 = *(const float2*)&als[S][b * LR + kofs];     \
            _Pragma("unroll")                                             \
            for (int c = 0; c < 8; ++c)                                   \
                acc[c][b] += WREG[c].x * a2.x + WREG[c].y * a2.y;         \
        }                                                                 \
    } while (0)

    float acc[8][16];
    #pragma unroll
    for (int c = 0; c < 8; ++c)
        #pragma unroll
        for (int b = 0; b < 16; ++b) acc[c][b] = 0.0f;

    float2 wA[8], wB[8];
    stageA(0);
    LOADW(wA, 0);                                 // 16 vmem ops in flight

    #pragma unroll 1
    for (int t = 0; t < NT; t += 2) {
        // even phase: compute buf0 with wA
        stageA(t + 1);                            // NT even => t+1 < NT always
        LOADW(wB, t + 1);
        asm volatile("s_waitcnt vmcnt(16)" ::: "memory");  // s(t),w(t) done
        __builtin_amdgcn_s_barrier();
        __builtin_amdgcn_sched_barrier(0);
        COMPUTE(0, wA);
        __builtin_amdgcn_sched_barrier(0);
        __builtin_amdgcn_s_barrier();

        // odd phase: compute buf1 with wB
        if (t + 2 < NT) {
            stageA(t + 2);
            LOADW(wA, t + 2);
            asm volatile("s_waitcnt vmcnt(16)" ::: "memory");
        } else {
            asm volatile("s_waitcnt vmcnt(0)" ::: "memory");
        }
        __builtin_amdgcn_s_barrier();
        __builtin_amdgcn_sched_barrier(0);
        COMPUTE(1, wB);
        __builtin_amdgcn_sched_barrier(0);
        __builtin_amdgcn_s_barrier();
    }

    // in-row (16-lane) rotate-add reduce: 4 DPP rounds, register-only
    #pragma unroll
    for (int c = 0; c < 8; ++c)
        #pragma unroll
        for (int b = 0; b < 16; ++b) acc[c][b] = dpp_ror_add<0x121>(acc[c][b]);
    #pragma unroll
    for (int c = 0; c < 8; ++c)
        #pragma unroll
        for (int b = 0; b < 16; ++b) acc[c][b] = dpp_ror_add<0x122>(acc[c][b]);
    #pragma unroll
    for (int c = 0; c < 8; ++c)
        #pragma unroll
        for (int b = 0; b < 16; ++b) acc[c][b] = dpp_ror_add<0x124>(acc[c][b]);
    #pragma unroll
    for (int c = 0; c < 8; ++c)
        #pragma unroll
        for (int b = 0; b < 16; ++b) acc[c][b] = dpp_ror_add<0x128>(acc[c][b]);

    // 4 writer lanes per wave store their row-sums (16 partials total)
    if ((lane & 15) == 0) {
        float* rp = redls + (wv * 4 + (lane >> 4)) * 128;
        #pragma unroll
        for (int c = 0; c < 8; ++c)
            #pragma unroll
            for (int b = 0; b < 16; b += 2)
                *(float2*)&rp[c * 16 + b] = make_float2(acc[c][b], acc[c][b + 1]);
    }
    __syncthreads();

    // final: 128 threads, one (col,b) each; sum 16 partials (fixed order)
    if (threadIdx.x < 128) {
        const int c = threadIdx.x >> 4;
        const int b = threadIdx.x & 15;
        float s = 0.0f;
        #pragma unroll
        for (int j = 0; j < 16; ++j) s += redls[j * 128 + c * 16 + b];
        const int o = obase + c;
        s += bias[o];
        if (MODE == 0) {
            s = s / (1.0f + expf(-s));            // silu
            out[(size_t)b * HALF + o] = s;        // H b-major [16][HALF]
        } else {
            s = tanhf(s);
            out[(size_t)b * (HALF * 2) + o * 2 + g] = s;
        }
    }

#undef LOADW
#undef COMPUTE
}

extern "C" void kernel_launch(void* const* d_in, const int* in_sizes, int n_in,
                              void* d_out, int out_size, void* d_ws, size_t ws_size,
                              hipStream_t stream) {
    const float* x     = (const float*)d_in[0];
    const float* taper = (const float*)d_in[1];
    const float* cW1   = (const float*)d_in[2];
    const float* cb1   = (const float*)d_in[3];
    const float* cW2   = (const float*)d_in[4];
    const float* cb2   = (const float*)d_in[5];
    const float* pW1   = (const float*)d_in[6];
    const float* pb1   = (const float*)d_in[7];
    const float* pW2   = (const float*)d_in[8];
    const float* pb2   = (const float*)d_in[9];
    float* out = (float*)d_out;
    float* ws  = (float*)d_ws;

    float* phases_b = ws;                         // [16][4096]
    float* tdiff_b  = ws + 65536;                 // [16][4096]
    float* H1_b     = ws + 131072;                // [16][2048]
    float* H2_b     = ws + 163840;                // [16][2048]

    phase_tdiff_kernel<<<BB * TT / 4, 256, 0, stream>>>(x, taper, phases_b, tdiff_b);
    gemm_kernel<TT, 0><<<512, 256, 0, stream>>>(phases_b, cW1, cb1, H1_b,
                                                tdiff_b, pW1, pb1, H2_b);
    gemm_kernel<HALF, 1><<<512, 256, 0, stream>>>(H1_b, cW2, cb2, out,
                                                  H2_b, pW2, pb2, out);
}